// Round 1
// baseline (113.026 us; speedup 1.0000x reference)
//
#include <hip/hip_runtime.h>

// Problem constants (reference: x = (16, 3, 512, 512) fp32)
constexpr int Hc = 512;
constexpr int Wc = 512;
constexpr int Cc = 3;
constexpr int QW = Wc / 4;  // quads (4 pixels) per row = 128

// Sobel (kornia normalized, cross-correlation as lax.conv does):
// gx = [[-1,0,1],[-2,0,2],[-1,0,1]]/8 ,  gy = gx^T
// gx = 0.125*(r0[w+1]-r0[w-1]) + 0.25*(r1[w+1]-r1[w-1]) + 0.125*(r2[w+1]-r2[w-1])
// gy = 0.125*(r2[w-1]-r0[w-1]) + 0.25*(r2[w]-r0[w]) + 0.125*(r2[w+1]-r0[w+1])
// (r0 = row h-1, r2 = row h+1; 'edge' padding = clamp)

__global__ __launch_bounds__(256) void sobel_mag_angle_kernel(
    const float* __restrict__ x, float* __restrict__ out, int B) {
    int tid = blockIdx.x * 256 + threadIdx.x;
    int q = tid % QW;
    int h = (tid / QW) % Hc;
    int b = tid / (QW * Hc);
    if (b >= B) return;
    int w0 = q * 4;

    const float* xb = x + (size_t)b * Cc * Hc * Wc;

    float gxa[3][4], gya[3][4];

    bool interior = (h >= 1) && (h <= Hc - 2) && (w0 >= 4) && (w0 <= Wc - 8);
    if (interior) {
        // Fast path: aligned float4 center loads + scalar halo columns.
#pragma unroll
        for (int c = 0; c < Cc; ++c) {
            const float* p = xb + c * (Hc * Wc) + h * Wc + w0;
            float4 m0 = *(const float4*)(p - Wc);
            float4 m1 = *(const float4*)(p);
            float4 m2 = *(const float4*)(p + Wc);
            float l0 = p[-Wc - 1], e0 = p[-Wc + 4];
            float l1 = p[-1],      e1 = p[4];
            float l2 = p[Wc - 1],  e2 = p[Wc + 4];
            // cols j = 0..5 map to w0-1 .. w0+4
            float row0[6] = {l0, m0.x, m0.y, m0.z, m0.w, e0};
            float row1[6] = {l1, m1.x, m1.y, m1.z, m1.w, e1};
            float row2[6] = {l2, m2.x, m2.y, m2.z, m2.w, e2};
#pragma unroll
            for (int i = 0; i < 4; ++i) {
                float t0 = row0[i + 2] - row0[i];
                float t1 = row1[i + 2] - row1[i];
                float t2 = row2[i + 2] - row2[i];
                gxa[c][i] = 0.125f * t0 + 0.25f * t1 + 0.125f * t2;
                float u0 = row2[i]     - row0[i];
                float u1 = row2[i + 1] - row0[i + 1];
                float u2 = row2[i + 2] - row0[i + 2];
                gya[c][i] = 0.125f * u0 + 0.25f * u1 + 0.125f * u2;
            }
        }
    } else {
        // Boundary path: per-element clamped ('edge' padding) loads.
#pragma unroll
        for (int c = 0; c < Cc; ++c) {
            const float* p = xb + c * (Hc * Wc);
#pragma unroll
            for (int i = 0; i < 4; ++i) {
                int w = w0 + i;
                int wm = w - 1 < 0 ? 0 : w - 1;
                int wp = w + 1 > Wc - 1 ? Wc - 1 : w + 1;
                int hm = h - 1 < 0 ? 0 : h - 1;
                int hp = h + 1 > Hc - 1 ? Hc - 1 : h + 1;
                float a00 = p[hm * Wc + wm], a01 = p[hm * Wc + w], a02 = p[hm * Wc + wp];
                float a10 = p[h * Wc + wm],                         a12 = p[h * Wc + wp];
                float a20 = p[hp * Wc + wm], a21 = p[hp * Wc + w], a22 = p[hp * Wc + wp];
                gxa[c][i] = 0.125f * (a02 - a00) + 0.25f * (a12 - a10) + 0.125f * (a22 - a20);
                gya[c][i] = 0.125f * (a20 - a00) + 0.25f * (a21 - a01) + 0.125f * (a22 - a02);
            }
        }
    }

    // Per-pixel: per-channel magnitude, first-occurrence argmax (strict >),
    // then magnitude of selected channel (same fp expression => reuse) and
    // clipped div angle.
    float mout[4], aout[4];
#pragma unroll
    for (int i = 0; i < 4; ++i) {
        float bgx = gxa[0][i], bgy = gya[0][i];
        float bm = sqrtf(bgx * bgx + bgy * bgy + 1e-9f);
#pragma unroll
        for (int c = 1; c < Cc; ++c) {
            float cgx = gxa[c][i], cgy = gya[c][i];
            float m = sqrtf(cgx * cgx + cgy * cgy + 1e-9f);
            if (m > bm) { bm = m; bgx = cgx; bgy = cgy; }
        }
        mout[i] = bm;
        float yt = (bgy == 0.0f) ? 1e-9f : bgy;
        float a = bgx / yt;
        aout[i] = fminf(fmaxf(a, -10.0f), 10.0f);
    }

    size_t obase = ((size_t)b * Hc + h) * Wc + w0;
    size_t npix = (size_t)B * Hc * Wc;
    *(float4*)(out + obase) = make_float4(mout[0], mout[1], mout[2], mout[3]);
    *(float4*)(out + npix + obase) = make_float4(aout[0], aout[1], aout[2], aout[3]);
}

extern "C" void kernel_launch(void* const* d_in, const int* in_sizes, int n_in,
                              void* d_out, int out_size, void* d_ws, size_t ws_size,
                              hipStream_t stream) {
    const float* x = (const float*)d_in[0];
    float* out = (float*)d_out;
    int B = in_sizes[0] / (Cc * Hc * Wc);  // 16
    int total_threads = B * Hc * QW;       // one thread per 4-pixel quad
    int blocks = (total_threads + 255) / 256;
    sobel_mag_angle_kernel<<<blocks, 256, 0, stream>>>(x, out, B);
}

// Round 3
// 106.445 us; speedup vs baseline: 1.0618x; 1.0618x over previous
//
#include <hip/hip_runtime.h>

// x: (16, 3, 512, 512) fp32. Outputs: magnitude (b,h,w), angle (b,h,w) concat flat.
// Sobel (kornia normalized, cross-correlation):
//   gx = 0.125*(r0[w+1]-r0[w-1]) + 0.25*(r1[w+1]-r1[w-1]) + 0.125*(r2[w+1]-r2[w-1])
//   gy = 0.125*(r2[w-1]-r0[w-1]) + 0.25*(r2[w]-r0[w]) + 0.125*(r2[w+1]-r0[w+1])
// 'edge' padding == clamped indices.

constexpr int Hc = 512;
constexpr int Wc = 512;
constexpr int Cc = 3;
constexpr int PW = 8;             // pixels per thread along w
constexpr int TPR = Wc / PW;      // 64 threads per row == one wave per row

__global__ __launch_bounds__(256, 4) void sobel_mag_angle_kernel(
    const float* __restrict__ x, float* __restrict__ out, int B) {
    int tid = blockIdx.x * 256 + threadIdx.x;
    int lane = tid & (TPR - 1);            // 0..63, wave-aligned: one wave = one row
    int h = (tid / TPR) & (Hc - 1);
    int b = tid / (TPR * Hc);
    int w0 = lane * PW;

    const float* xb = x + (size_t)b * Cc * Hc * Wc;
    // Uniform clamped addressing (edge padding) — no divergent boundary path.
    int hm = h > 0 ? h - 1 : 0;
    int hp = h < Hc - 1 ? h + 1 : h;
    int wl = w0 > 0 ? w0 - 1 : 0;          // only lane 0 clamps
    int wr = w0 + PW < Wc ? w0 + PW : Wc - 1;  // only lane 63 clamps

    float bm[PW], bgx[PW], bgy[PW];

#pragma unroll
    for (int c = 0; c < Cc; ++c) {
        const float* base = xb + c * (Hc * Wc);
        const float* pm = base + hm * Wc;
        const float* pc = base + h * Wc;
        const float* pp = base + hp * Wc;
        float4 a0 = *(const float4*)(pm + w0), a1 = *(const float4*)(pm + w0 + 4);
        float4 b0 = *(const float4*)(pc + w0), b1 = *(const float4*)(pc + w0 + 4);
        float4 c0 = *(const float4*)(pp + w0), c1 = *(const float4*)(pp + w0 + 4);
        float lm = pm[wl], rm = pm[wr];
        float lc = pc[wl], rc = pc[wr];
        float lp = pp[wl], rp = pp[wr];
        // columns 0..9 map to w0-1 .. w0+8
        float r0[10] = {lm, a0.x, a0.y, a0.z, a0.w, a1.x, a1.y, a1.z, a1.w, rm};
        float r1[10] = {lc, b0.x, b0.y, b0.z, b0.w, b1.x, b1.y, b1.z, b1.w, rc};
        float r2[10] = {lp, c0.x, c0.y, c0.z, c0.w, c1.x, c1.y, c1.z, c1.w, rp};
#pragma unroll
        for (int i = 0; i < PW; ++i) {
            float t0 = r0[i + 2] - r0[i];
            float t1 = r1[i + 2] - r1[i];
            float t2 = r2[i + 2] - r2[i];
            float gx = 0.125f * (t0 + t2) + 0.25f * t1;
            float u0 = r2[i]     - r0[i];       // CSE'd across i by GVN
            float u1 = r2[i + 1] - r0[i + 1];
            float u2 = r2[i + 2] - r0[i + 2];
            float gy = 0.125f * (u0 + u2) + 0.25f * u1;
            float m = __builtin_amdgcn_sqrtf(gx * gx + gy * gy + 1e-9f);
            if (c == 0) {
                bm[i] = m; bgx[i] = gx; bgy[i] = gy;
            } else {
                bool gt = m > bm[i];            // strict > = first-occurrence argmax
                bm[i] = gt ? m : bm[i];
                bgx[i] = gt ? gx : bgx[i];
                bgy[i] = gt ? gy : bgy[i];
            }
        }
    }

    float mo[PW], ao[PW];
#pragma unroll
    for (int i = 0; i < PW; ++i) {
        mo[i] = bm[i];
        float yt = (bgy[i] == 0.0f) ? 1e-9f : bgy[i];
        float a = bgx[i] * __builtin_amdgcn_rcpf(yt);   // ~2 ulp; clipped to ±10 anyway
        ao[i] = fminf(fmaxf(a, -10.0f), 10.0f);
    }

    size_t obase = ((size_t)b * Hc + h) * Wc + w0;
    size_t npix = (size_t)B * Hc * Wc;
    *(float4*)(out + obase)            = make_float4(mo[0], mo[1], mo[2], mo[3]);
    *(float4*)(out + obase + 4)        = make_float4(mo[4], mo[5], mo[6], mo[7]);
    *(float4*)(out + npix + obase)     = make_float4(ao[0], ao[1], ao[2], ao[3]);
    *(float4*)(out + npix + obase + 4) = make_float4(ao[4], ao[5], ao[6], ao[7]);
}

extern "C" void kernel_launch(void* const* d_in, const int* in_sizes, int n_in,
                              void* d_out, int out_size, void* d_ws, size_t ws_size,
                              hipStream_t stream) {
    const float* x = (const float*)d_in[0];
    float* out = (float*)d_out;
    int B = in_sizes[0] / (Cc * Hc * Wc);            // 16
    int total_threads = B * Hc * TPR;                // 524288
    int blocks = total_threads / 256;                // 2048, exact
    sobel_mag_angle_kernel<<<blocks, 256, 0, stream>>>(x, out, B);
}

// Round 4
// 101.778 us; speedup vs baseline: 1.1105x; 1.0459x over previous
//
#include <hip/hip_runtime.h>

// x: (16, 3, 512, 512) fp32 -> magnitude (b,h,w) ++ angle (b,h,w), fp32.
// Sobel (kornia normalized, cross-correlation, 'edge' padding = clamp):
//   gx = 0.125*(r0[w+1]-r0[w-1]) + 0.25*(r1[w+1]-r1[w-1]) + 0.125*(r2[w+1]-r2[w-1])
//   gy = 0.125*(r2[w-1]-r0[w-1]) + 0.25*(r2[w]-r0[w]) + 0.125*(r2[w+1]-r0[w+1])
// One wave = one row-pair: lane holds 8 contiguous px; halo columns come from
// neighbor lanes via shuffle (zero scalar loads). 2 rows/thread for vertical reuse.

constexpr int Hc = 512;
constexpr int Wc = 512;
constexpr int Cc = 3;
constexpr int PW = 8;             // pixels per lane along w
constexpr int RT = 2;             // output rows per thread
constexpr int TPR = Wc / PW;      // 64 lanes = full row

__global__ __launch_bounds__(256, 4) void sobel_mag_angle_kernel(
    const float* __restrict__ x, float* __restrict__ out, int B) {
    int tid = blockIdx.x * 256 + threadIdx.x;
    int lane = tid & 63;
    int hh = (tid >> 6) & (Hc / RT - 1);   // row-pair index 0..255
    int b = tid >> 14;                      // 6 + log2(256)
    int w0 = lane << 3;
    int h0 = hh * RT;

    const float* xb = x + (size_t)b * Cc * Hc * Wc;
    int rm = h0 > 0 ? h0 - 1 : 0;                 // clamped row above
    int rp = h0 + RT < Hc ? h0 + RT : Hc - 1;     // clamped row below pair

    bool l0 = (lane == 0), l63 = (lane == 63);

    float bm[RT][PW], bgx[RT][PW], bgy[RT][PW];

#pragma unroll
    for (int c = 0; c < Cc; ++c) {
        const float* base = xb + c * (Hc * Wc);
        const float* pr[4] = { base + rm * Wc, base + h0 * Wc,
                               base + (h0 + 1) * Wc, base + rp * Wc };
        float row[4][10];   // cols 0..9 = w0-1 .. w0+8
#pragma unroll
        for (int r = 0; r < 4; ++r) {
            float4 v0 = *(const float4*)(pr[r] + w0);
            float4 v1 = *(const float4*)(pr[r] + w0 + 4);
            float lh = __shfl_up(v1.w, 1);          // neighbor's px w0-1
            lh = l0 ? v0.x : lh;                    // w=-1 clamps to w=0
            float rh = __shfl_down(v0.x, 1);        // neighbor's px w0+8
            rh = l63 ? v1.w : rh;                   // w=512 clamps to w=511
            row[r][0] = lh;
            row[r][1] = v0.x; row[r][2] = v0.y; row[r][3] = v0.z; row[r][4] = v0.w;
            row[r][5] = v1.x; row[r][6] = v1.y; row[r][7] = v1.z; row[r][8] = v1.w;
            row[r][9] = rh;
        }
#pragma unroll
        for (int rr = 0; rr < RT; ++rr) {
            // output row h0+rr uses input rows rr, rr+1, rr+2
#pragma unroll
            for (int i = 0; i < PW; ++i) {
                float t0 = row[rr][i + 2]     - row[rr][i];
                float t1 = row[rr + 1][i + 2] - row[rr + 1][i];
                float t2 = row[rr + 2][i + 2] - row[rr + 2][i];
                float gx = 0.125f * (t0 + t2) + 0.25f * t1;
                float u0 = row[rr + 2][i]     - row[rr][i];
                float u1 = row[rr + 2][i + 1] - row[rr][i + 1];
                float u2 = row[rr + 2][i + 2] - row[rr][i + 2];
                float gy = 0.125f * (u0 + u2) + 0.25f * u1;
                float m = __builtin_amdgcn_sqrtf(gx * gx + gy * gy + 1e-9f);
                if (c == 0) {
                    bm[rr][i] = m; bgx[rr][i] = gx; bgy[rr][i] = gy;
                } else {
                    bool gt = m > bm[rr][i];   // strict > = first-occurrence argmax
                    bm[rr][i]  = gt ? m  : bm[rr][i];
                    bgx[rr][i] = gt ? gx : bgx[rr][i];
                    bgy[rr][i] = gt ? gy : bgy[rr][i];
                }
            }
        }
    }

    size_t npix = (size_t)B * Hc * Wc;
#pragma unroll
    for (int rr = 0; rr < RT; ++rr) {
        float mo[PW], ao[PW];
#pragma unroll
        for (int i = 0; i < PW; ++i) {
            mo[i] = bm[rr][i];
            float yt = (bgy[rr][i] == 0.0f) ? 1e-9f : bgy[rr][i];
            float a = bgx[rr][i] * __builtin_amdgcn_rcpf(yt);  // clipped to ±10 anyway
            ao[i] = fminf(fmaxf(a, -10.0f), 10.0f);
        }
        size_t obase = ((size_t)b * Hc + (h0 + rr)) * Wc + w0;
        *(float4*)(out + obase)            = make_float4(mo[0], mo[1], mo[2], mo[3]);
        *(float4*)(out + obase + 4)        = make_float4(mo[4], mo[5], mo[6], mo[7]);
        *(float4*)(out + npix + obase)     = make_float4(ao[0], ao[1], ao[2], ao[3]);
        *(float4*)(out + npix + obase + 4) = make_float4(ao[4], ao[5], ao[6], ao[7]);
    }
}

extern "C" void kernel_launch(void* const* d_in, const int* in_sizes, int n_in,
                              void* d_out, int out_size, void* d_ws, size_t ws_size,
                              hipStream_t stream) {
    const float* x = (const float*)d_in[0];
    float* out = (float*)d_out;
    int B = in_sizes[0] / (Cc * Hc * Wc);              // 16
    int total_threads = B * (Hc / RT) * TPR;           // 262144
    int blocks = total_threads / 256;                  // 1024, exact
    sobel_mag_angle_kernel<<<blocks, 256, 0, stream>>>(x, out, B);
}

// Round 5
// 98.432 us; speedup vs baseline: 1.1483x; 1.0340x over previous
//
#include <hip/hip_runtime.h>

// x: (16, 3, 512, 512) fp32 -> magnitude (b,h,w) ++ angle (b,h,w), fp32.
// Sobel (kornia normalized, cross-correlation, 'edge' padding = clamp):
//   gx = 0.125*(r0[w+1]-r0[w-1]) + 0.25*(r1[w+1]-r1[w-1]) + 0.125*(r2[w+1]-r2[w-1])
//   gy = 0.125*(r2[w-1]-r0[w-1]) + 0.25*(r2[w]-r0[w]) + 0.125*(r2[w+1]-r0[w+1])
// Thread = 4 px x 2 output rows. All 27 loads per thread are mutually
// independent (f4 + 2 clamped scalars per (ch,row)) -> max MLP, no
// load->shuffle dependency chains.

constexpr int Hc = 512;
constexpr int Wc = 512;
constexpr int Cc = 3;

__global__ __launch_bounds__(256, 4) void sobel_mag_angle_kernel(
    const float* __restrict__ x, float* __restrict__ out, int B) {
    int tid = blockIdx.x * 256 + threadIdx.x;
    int l  = tid & 127;             // 128 threads span one row (4 px each)
    int hh = (tid >> 7) & 255;      // row-pair index
    int b  = tid >> 15;
    int w0 = l << 2;
    int h0 = hh << 1;

    // Clamped halo indices ('edge' padding) — computed once, uniform cost.
    int wl = (w0 == 0) ? 0 : w0 - 1;
    int wr = (w0 + 4 < Wc) ? w0 + 4 : Wc - 1;
    int rm = (h0 == 0) ? 0 : h0 - 1;
    int rp = (h0 + 2 < Hc) ? h0 + 2 : Hc - 1;

    const float* xb = x + (size_t)b * Cc * Hc * Wc;

    float bm[2][4], bgx[2][4], bgy[2][4];

#pragma unroll
    for (int c = 0; c < Cc; ++c) {
        const float* base = xb + c * (Hc * Wc);
        const float* pr[4] = { base + rm * Wc, base + h0 * Wc,
                               base + (h0 + 1) * Wc, base + rp * Wc };
        // cols 0..5 = image cols w0-1 .. w0+4 (clamped at edges)
        float col[4][6];
#pragma unroll
        for (int r = 0; r < 4; ++r) {
            float4 v = *(const float4*)(pr[r] + w0);
            float lh = pr[r][wl];
            float rh = pr[r][wr];
            col[r][0] = lh;
            col[r][1] = v.x; col[r][2] = v.y; col[r][3] = v.z; col[r][4] = v.w;
            col[r][5] = rh;
        }
        // horizontal diffs, shared between the two output rows
        float t[4][4];
#pragma unroll
        for (int r = 0; r < 4; ++r)
#pragma unroll
            for (int i = 0; i < 4; ++i)
                t[r][i] = col[r][i + 2] - col[r][i];
        // vertical diffs
        float u[2][6];
#pragma unroll
        for (int rr = 0; rr < 2; ++rr)
#pragma unroll
            for (int j = 0; j < 6; ++j)
                u[rr][j] = col[rr + 2][j] - col[rr][j];
#pragma unroll
        for (int rr = 0; rr < 2; ++rr) {
#pragma unroll
            for (int i = 0; i < 4; ++i) {
                float gx = 0.125f * (t[rr][i] + t[rr + 2][i]) + 0.25f * t[rr + 1][i];
                float gy = 0.125f * (u[rr][i] + u[rr][i + 2]) + 0.25f * u[rr][i + 1];
                float m = __builtin_amdgcn_sqrtf(gx * gx + gy * gy + 1e-9f);
                if (c == 0) {
                    bm[rr][i] = m; bgx[rr][i] = gx; bgy[rr][i] = gy;
                } else {
                    bool gt = m > bm[rr][i];   // strict > = first-occurrence argmax
                    bm[rr][i]  = gt ? m  : bm[rr][i];
                    bgx[rr][i] = gt ? gx : bgx[rr][i];
                    bgy[rr][i] = gt ? gy : bgy[rr][i];
                }
            }
        }
    }

    size_t npix = (size_t)B * Hc * Wc;
#pragma unroll
    for (int rr = 0; rr < 2; ++rr) {
        float mo[4], ao[4];
#pragma unroll
        for (int i = 0; i < 4; ++i) {
            mo[i] = bm[rr][i];
            float yt = (bgy[rr][i] == 0.0f) ? 1e-9f : bgy[rr][i];
            float a = bgx[rr][i] * __builtin_amdgcn_rcpf(yt);  // clipped to ±10 anyway
            ao[i] = fminf(fmaxf(a, -10.0f), 10.0f);
        }
        size_t obase = ((size_t)b * Hc + (h0 + rr)) * Wc + w0;
        *(float4*)(out + obase)        = make_float4(mo[0], mo[1], mo[2], mo[3]);
        *(float4*)(out + npix + obase) = make_float4(ao[0], ao[1], ao[2], ao[3]);
    }
}

extern "C" void kernel_launch(void* const* d_in, const int* in_sizes, int n_in,
                              void* d_out, int out_size, void* d_ws, size_t ws_size,
                              hipStream_t stream) {
    const float* x = (const float*)d_in[0];
    float* out = (float*)d_out;
    int B = in_sizes[0] / (Cc * Hc * Wc);            // 16
    int total_threads = B * (Hc / 2) * (Wc / 4);     // 524288
    int blocks = total_threads / 256;                // 2048, exact
    sobel_mag_angle_kernel<<<blocks, 256, 0, stream>>>(x, out, B);
}